// Round 1
// baseline (262.698 us; speedup 1.0000x reference)
//
#include <hip/hip_runtime.h>

// LinearAttention: N=8, L=S=4096, H=8, D=M=64, fp32.
// phase1: KVt[n,h,d,m] = sum_s phi(K)[s,d]*mask[s]*V[s,m];  Ksum[n,h,d] = sum_s phi(K)[s,d]*mask[s]
// phase2: out[n,l,h,m] = (phi(Q)[l,:]·KVt[:,m]) / (phi(Q)[l,:]·Ksum + eps)

#define SLEN 4096
#define LLEN 4096
#define NB   8
#define HH   8
#define DD   64
#define MM   64
#define HD   512   // H*D row stride in elements

__device__ __forceinline__ float phi(float x) {
    return x > 0.0f ? x + 1.0f : __expf(x);
}

__device__ __forceinline__ void fma4(float4& a, float s, float4 b) {
    a.x = fmaf(s, b.x, a.x);
    a.y = fmaf(s, b.y, a.y);
    a.z = fmaf(s, b.z, a.z);
    a.w = fmaf(s, b.w, a.w);
}

// ---------------- Phase 1: KVt + Ksum ----------------
// grid (S/512, N*H), block 256.  Each block: 512 s-rows, 8 tiles of 64.
__global__ __launch_bounds__(256)
void la_phase1(const float* __restrict__ Kg, const float* __restrict__ Vg,
               const float* __restrict__ maskg,
               float* __restrict__ KVt, float* __restrict__ Ksum) {
    __shared__ float Ks[64 * 64];       // 16 KB
    __shared__ float Vs[64 * 64];       // 16 KB
    __shared__ float Red[64 * 68];      // [d][m], padded row stride 68 (17 KB)
    __shared__ float KsB[16 * 64];      // ksum partial reduce (4 KB)

    const int tid  = threadIdx.x;
    const int nh   = blockIdx.y;
    const int n    = nh >> 3;
    const int h    = nh & 7;
    const int sbase = blockIdx.x * 512;

    const size_t base = (size_t)n * SLEN * HD + (size_t)h * DD;
    const float* mrow = maskg + (size_t)n * SLEN;

    const int col4 = (tid & 15) * 4;    // staging column (d or m)
    const int r0   = tid >> 4;          // staging row base 0..15

    const int lane = tid & 63;
    const int grp  = tid >> 6;          // wave id 0..3 (s-split group)
    const int d0   = (lane & 7) * 8;    // thread's 8 d's
    const int m0   = (lane >> 3) * 8;   // thread's 8 m's

    float4 acc[8][2];
    #pragma unroll
    for (int i = 0; i < 8; ++i) {
        acc[i][0] = make_float4(0.f, 0.f, 0.f, 0.f);
        acc[i][1] = make_float4(0.f, 0.f, 0.f, 0.f);
    }
    float4 ksp = make_float4(0.f, 0.f, 0.f, 0.f);

    for (int t = 0; t < 8; ++t) {
        const int srow0 = sbase + t * 64;
        // ---- stage 64 rows of K (phi'd, masked) and V ----
        #pragma unroll
        for (int rr = 0; rr < 4; ++rr) {
            const int row = r0 + rr * 16;
            const int s   = srow0 + row;
            const size_t goff = base + (size_t)s * HD + col4;
            float4 kf = *(const float4*)(Kg + goff);
            const float mmv = mrow[s];
            kf.x = phi(kf.x) * mmv;
            kf.y = phi(kf.y) * mmv;
            kf.z = phi(kf.z) * mmv;
            kf.w = phi(kf.w) * mmv;
            *(float4*)&Ks[row * 64 + col4] = kf;
            ksp.x += kf.x; ksp.y += kf.y; ksp.z += kf.z; ksp.w += kf.w;
            *(float4*)&Vs[row * 64 + col4] = *(const float4*)(Vg + goff);
        }
        __syncthreads();
        // ---- outer-product accumulate, 4-way s-split across waves ----
        #pragma unroll 4
        for (int s = grp; s < 64; s += 4) {
            float4 ka = *(const float4*)&Ks[s * 64 + d0];
            float4 kb = *(const float4*)&Ks[s * 64 + d0 + 4];
            float4 va = *(const float4*)&Vs[s * 64 + m0];
            float4 vb = *(const float4*)&Vs[s * 64 + m0 + 4];
            const float kk[8] = {ka.x, ka.y, ka.z, ka.w, kb.x, kb.y, kb.z, kb.w};
            #pragma unroll
            for (int di = 0; di < 8; ++di) {
                fma4(acc[di][0], kk[di], va);
                fma4(acc[di][1], kk[di], vb);
            }
        }
        __syncthreads();
    }

    // ---- combine the 4 wave-groups' tiles in LDS ----
    if (grp == 0) {
        #pragma unroll
        for (int di = 0; di < 8; ++di) {
            *(float4*)&Red[(d0 + di) * 68 + m0]     = acc[di][0];
            *(float4*)&Red[(d0 + di) * 68 + m0 + 4] = acc[di][1];
        }
    }
    __syncthreads();
    for (int g = 1; g < 4; ++g) {
        if (grp == g) {
            #pragma unroll
            for (int di = 0; di < 8; ++di) {
                float4* p0 = (float4*)&Red[(d0 + di) * 68 + m0];
                float4* p1 = (float4*)&Red[(d0 + di) * 68 + m0 + 4];
                float4 v0 = *p0, v1 = *p1;
                v0.x += acc[di][0].x; v0.y += acc[di][0].y; v0.z += acc[di][0].z; v0.w += acc[di][0].w;
                v1.x += acc[di][1].x; v1.y += acc[di][1].y; v1.z += acc[di][1].z; v1.w += acc[di][1].w;
                *p0 = v0; *p1 = v1;
            }
        }
        __syncthreads();
    }

    // ---- Ksum block reduce + atomic ----
    *(float4*)&KsB[r0 * 64 + col4] = ksp;
    __syncthreads();
    if (tid < 64) {
        float ssum = 0.f;
        #pragma unroll
        for (int r = 0; r < 16; ++r) ssum += KsB[r * 64 + tid];
        atomicAdd(&Ksum[nh * 64 + tid], ssum);
    }

    // ---- KVt atomic accumulate (coalesced, [d][m] layout) ----
    for (int k2 = 0; k2 < 16; ++k2) {
        const int idx = k2 * 256 + tid;
        atomicAdd(&KVt[(size_t)nh * 4096 + idx], Red[(idx >> 6) * 68 + (idx & 63)]);
    }
}

// ---------------- Phase 2: out = phi(Q) @ KVt, normalized ----------------
// grid (L/128, N*H), block 128 (2 waves, each owns 64 l-rows).
__global__ __launch_bounds__(128)
void la_phase2(const float* __restrict__ Qg, const float* __restrict__ KVt,
               const float* __restrict__ Ksum, float* __restrict__ Og) {
    __shared__ float Qs[128 * 68];  // 34 KB, phi'd Q, padded stride 68 (16B-aligned, bank-rotating)
    __shared__ float KVs[64 * 64];  // 16 KB, [d][m]
    __shared__ float KSs[64];

    const int tid = threadIdx.x;
    const int nh  = blockIdx.y;
    const int n   = nh >> 3;
    const int h   = nh & 7;
    const int lbase = blockIdx.x * 128;

    // ---- stage phi(Q) (each element phi'd exactly once) ----
    const int col4 = (tid & 15) * 4;
    const int r0   = tid >> 4;     // 0..7
    #pragma unroll
    for (int rr = 0; rr < 16; ++rr) {
        const int row = r0 + rr * 8;
        const int l   = lbase + row;
        float4 q = *(const float4*)&Qg[((size_t)(n * LLEN + l) * HH + h) * DD + col4];
        q.x = phi(q.x); q.y = phi(q.y); q.z = phi(q.z); q.w = phi(q.w);
        *(float4*)&Qs[row * 68 + col4] = q;
    }
    // ---- stage KVt and Ksum (L2-resident, tiny) ----
    #pragma unroll
    for (int k2 = 0; k2 < 8; ++k2) {
        const int f = k2 * 128 + tid;
        *(float4*)&KVs[f * 4] = *(const float4*)&KVt[(size_t)nh * 4096 + f * 4];
    }
    if (tid < 16) *(float4*)&KSs[tid * 4] = *(const float4*)&Ksum[nh * 64 + tid * 4];
    __syncthreads();

    const int wv   = tid >> 6;          // 0..1
    const int lane = tid & 63;
    const int tx   = lane & 7;
    const int ty   = lane >> 3;
    const int rowbase = wv * 64 + ty;   // rows rowbase + 8*i (stride-8: conflict-free Qs reads)
    const int m0 = tx * 8;

    float4 acc[8][2];
    float  den[8];
    #pragma unroll
    for (int i = 0; i < 8; ++i) {
        acc[i][0] = make_float4(0.f, 0.f, 0.f, 0.f);
        acc[i][1] = make_float4(0.f, 0.f, 0.f, 0.f);
        den[i] = 0.f;
    }

    for (int d4 = 0; d4 < 16; ++d4) {
        float4 q4[8];
        #pragma unroll
        for (int i = 0; i < 8; ++i)
            q4[i] = *(const float4*)&Qs[(rowbase + 8 * i) * 68 + d4 * 4];
        const float4 ks = *(const float4*)&KSs[d4 * 4];
        #pragma unroll
        for (int i = 0; i < 8; ++i) {
            den[i] = fmaf(q4[i].x, ks.x, den[i]);
            den[i] = fmaf(q4[i].y, ks.y, den[i]);
            den[i] = fmaf(q4[i].z, ks.z, den[i]);
            den[i] = fmaf(q4[i].w, ks.w, den[i]);
        }
        #pragma unroll
        for (int dk = 0; dk < 4; ++dk) {
            const int d = d4 * 4 + dk;
            const float4 kv0 = *(const float4*)&KVs[d * 64 + m0];
            const float4 kv1 = *(const float4*)&KVs[d * 64 + m0 + 4];
            #pragma unroll
            for (int i = 0; i < 8; ++i) {
                const float qs = ((const float*)&q4[i])[dk];
                fma4(acc[i][0], qs, kv0);
                fma4(acc[i][1], qs, kv1);
            }
        }
    }

    // ---- normalize + store (coalesced float4) ----
    #pragma unroll
    for (int i = 0; i < 8; ++i) {
        const int l = lbase + rowbase + 8 * i;
        const float z = 1.0f / (den[i] + 1e-6f);
        float4 o0 = acc[i][0], o1 = acc[i][1];
        o0.x *= z; o0.y *= z; o0.z *= z; o0.w *= z;
        o1.x *= z; o1.y *= z; o1.z *= z; o1.w *= z;
        const size_t off = ((size_t)(n * LLEN + l) * HH + h) * MM + m0;
        *(float4*)&Og[off]     = o0;
        *(float4*)&Og[off + 4] = o1;
    }
}

extern "C" void kernel_launch(void* const* d_in, const int* in_sizes, int n_in,
                              void* d_out, int out_size, void* d_ws, size_t ws_size,
                              hipStream_t stream) {
    const float* Q    = (const float*)d_in[0];
    const float* K    = (const float*)d_in[1];
    const float* V    = (const float*)d_in[2];
    const float* mask = (const float*)d_in[3];
    float* out  = (float*)d_out;
    float* KVt  = (float*)d_ws;                 // [N*H][64][64] = 1 MB
    float* Ksum = KVt + (size_t)NB * HH * DD * MM;  // [N*H][64]

    hipMemsetAsync(d_ws, 0, ((size_t)NB * HH * DD * MM + (size_t)NB * HH * DD) * sizeof(float), stream);

    dim3 g1(SLEN / 512, NB * HH);
    la_phase1<<<g1, 256, 0, stream>>>(K, V, mask, KVt, Ksum);

    dim3 g2(LLEN / 128, NB * HH);
    la_phase2<<<g2, 128, 0, stream>>>(Q, KVt, Ksum, out);
}